// Round 1
// baseline (432.752 us; speedup 1.0000x reference)
//
#include <hip/hip_runtime.h>

typedef __attribute__((ext_vector_type(8))) short short8;
typedef __attribute__((ext_vector_type(4))) float f32x4;

#define B_    2
#define L_    2048
#define DIM_  1024
#define NH_   16
#define HEAD_ 64
#define M_    4096            // B_*L_
#define SZ_   4194304         // M_*DIM_ elements

__device__ __forceinline__ unsigned short f2bf(float f) {
  unsigned int u = __float_as_uint(f);
  u += 0x7FFFu + ((u >> 16) & 1u);          // RNE, finite inputs only
  return (unsigned short)(u >> 16);
}
__device__ __forceinline__ float bf2f(unsigned short b) {
  return __uint_as_float(((unsigned int)b) << 16);
}
__device__ __forceinline__ unsigned short f2h(float f) {
  _Float16 h = (_Float16)f;
  return __builtin_bit_cast(unsigned short, h);
}
__device__ __forceinline__ float h2f(unsigned short u) {
  return (float)__builtin_bit_cast(_Float16, u);
}

// C[m][n] = sum_k A[m][k] * W[n][k]   (both K-contiguous; W always fp32 source)
// A: fp32 (converted) or bf16; C: bf16 or fp32.
template<bool A_F32, bool C_F32>
__global__ __launch_bounds__(256) void gemm_bt(const void* __restrict__ Ap,
                                               const float* __restrict__ Wp,
                                               void* __restrict__ Cp,
                                               int Kdim, int Ndim) {
  __shared__ unsigned short Alds[128][72];   // +8 pad: 16B-aligned rows, balanced banks
  __shared__ unsigned short Blds[128][72];
  const int t    = threadIdx.x;
  const int m0   = blockIdx.x * 128;
  const int n0   = blockIdx.y * 128;
  const int lane = t & 63;
  const int wid  = t >> 6;
  const int lr   = lane & 15;
  const int lg   = lane >> 4;
  const int wm   = (wid >> 1) * 64;
  const int wn   = (wid & 1) * 64;
  const int srow = t >> 1;          // 0..127
  const int skh  = (t & 1) * 32;    // 0 or 32

  f32x4 acc[4][4] = {};

  for (int kb = 0; kb < Kdim; kb += 64) {
    // ---- stage A tile (128 x 64)
    if (A_F32) {
      const float* arow = (const float*)Ap + (size_t)(m0 + srow) * Kdim + kb + skh;
      unsigned short tmp[32];
#pragma unroll
      for (int j = 0; j < 8; ++j) {
        f32x4 v = ((const f32x4*)arow)[j];
#pragma unroll
        for (int c = 0; c < 4; ++c) tmp[j * 4 + c] = f2bf(v[c]);
      }
#pragma unroll
      for (int j = 0; j < 4; ++j)
        *(short8*)&Alds[srow][skh + j * 8] = *(const short8*)&tmp[j * 8];
    } else {
      const unsigned short* arow = (const unsigned short*)Ap + (size_t)(m0 + srow) * Kdim + kb + skh;
#pragma unroll
      for (int j = 0; j < 4; ++j)
        *(short8*)&Alds[srow][skh + j * 8] = ((const short8*)arow)[j];
    }
    // ---- stage B tile from W (fp32 -> bf16)
    {
      const float* brow = Wp + (size_t)(n0 + srow) * Kdim + kb + skh;
      unsigned short tmp[32];
#pragma unroll
      for (int j = 0; j < 8; ++j) {
        f32x4 v = ((const f32x4*)brow)[j];
#pragma unroll
        for (int c = 0; c < 4; ++c) tmp[j * 4 + c] = f2bf(v[c]);
      }
#pragma unroll
      for (int j = 0; j < 4; ++j)
        *(short8*)&Blds[srow][skh + j * 8] = *(const short8*)&tmp[j * 8];
    }
    __syncthreads();
#pragma unroll
    for (int ks = 0; ks < 2; ++ks) {
      short8 af[4], bfv[4];
#pragma unroll
      for (int i = 0; i < 4; ++i)
        af[i] = *(const short8*)&Alds[wm + i * 16 + lr][ks * 32 + lg * 8];
#pragma unroll
      for (int i = 0; i < 4; ++i)
        bfv[i] = *(const short8*)&Blds[wn + i * 16 + lr][ks * 32 + lg * 8];
#pragma unroll
      for (int i = 0; i < 4; ++i)
#pragma unroll
        for (int j = 0; j < 4; ++j)
          acc[i][j] = __builtin_amdgcn_mfma_f32_16x16x32_bf16(af[i], bfv[j], acc[i][j], 0, 0, 0);
    }
    __syncthreads();
  }

  // ---- epilogue: C write (D layout: col = lane&15, row = (lane>>4)*4 + r)
#pragma unroll
  for (int i = 0; i < 4; ++i) {
#pragma unroll
    for (int j = 0; j < 4; ++j) {
      const int grow = m0 + wm + i * 16 + lg * 4;
      const int gcol = n0 + wn + j * 16 + lr;
#pragma unroll
      for (int r = 0; r < 4; ++r) {
        float v = acc[i][j][r];
        if (C_F32) ((float*)Cp)[(size_t)(grow + r) * Ndim + gcol] = v;
        else ((unsigned short*)Cp)[(size_t)(grow + r) * Ndim + gcol] = f2bf(v);
      }
    }
  }
}

// One block per (q-block of 32 rows, b*16+head). 512 threads = 8 waves.
// Full 32x2048 score block in LDS: pass1 QK^T -> fp16; softmax stats; exp in
// place -> bf16 P; pass2 P·V with V^T staged per 128-key chunk.
__global__ __launch_bounds__(512) void attn_kernel(const unsigned short* __restrict__ QKV,
                                                   unsigned short* __restrict__ Xout) {
  __shared__ unsigned short S[32][2056];      // fp16 scores, then bf16 P (pad 8)
  __shared__ unsigned short VT[64][136];      // V^T chunk (pad 8)
  __shared__ float srowv[32];

  const int t    = threadIdx.x;
  const int wid  = t >> 6;
  const int lane = t & 63;
  const int lr   = lane & 15;
  const int lg   = lane >> 4;
  const int qb   = blockIdx.x;   // 0..63
  const int bh   = blockIdx.y;   // 0..31
  const int b    = bh >> 4;
  const int h    = bh & 15;
  const size_t base = (size_t)b * (L_ * DIM_) + (size_t)h * (L_ * HEAD_);
  const unsigned short* Qp = QKV + base;
  const unsigned short* Kp = QKV + (size_t)SZ_ + base;
  const unsigned short* Vp = QKV + 2 * (size_t)SZ_ + base;
  const int q0 = qb * 32;

  // ---- pass 1: S = (Q K^T) / 8 into LDS as fp16
  short8 qf[2][2];
#pragma unroll
  for (int mf = 0; mf < 2; ++mf)
#pragma unroll
    for (int ks = 0; ks < 2; ++ks)
      qf[mf][ks] = *(const short8*)&Qp[(size_t)(q0 + mf * 16 + lr) * HEAD_ + ks * 32 + lg * 8];

  for (int tI = 0; tI < 16; ++tI) {
    const int jb = wid * 256 + tI * 16;
    short8 kf[2];
#pragma unroll
    for (int ks = 0; ks < 2; ++ks)
      kf[ks] = *(const short8*)&Kp[(size_t)(jb + lr) * HEAD_ + ks * 32 + lg * 8];
#pragma unroll
    for (int mf = 0; mf < 2; ++mf) {
      f32x4 acc = {};
#pragma unroll
      for (int ks = 0; ks < 2; ++ks)
        acc = __builtin_amdgcn_mfma_f32_16x16x32_bf16(qf[mf][ks], kf[ks], acc, 0, 0, 0);
#pragma unroll
      for (int r = 0; r < 4; ++r)
        S[mf * 16 + lg * 4 + r][jb + lr] = f2h(acc[r] * 0.125f);
    }
  }
  __syncthreads();

  // ---- softmax: row max, then exp in place (bf16, unnormalized) + row sum
  {
    const int row = t >> 4;       // 16 threads per row, same wave
    const int c16 = t & 15;
    float m = -3.0e38f;
    for (int p = 0; p < 16; ++p) {
      short8 v = *(const short8*)&S[row][(c16 + p * 16) * 8];
#pragma unroll
      for (int e = 0; e < 8; ++e) m = fmaxf(m, h2f((unsigned short)v[e]));
    }
#pragma unroll
    for (int d = 1; d < 16; d <<= 1) m = fmaxf(m, __shfl_xor(m, d, 64));
    float s = 0.f;
    for (int p = 0; p < 16; ++p) {
      unsigned short* ptr = &S[row][(c16 + p * 16) * 8];
      short8 v = *(const short8*)ptr;
      short8 w;
#pragma unroll
      for (int e = 0; e < 8; ++e) {
        float pe = exp2f((h2f((unsigned short)v[e]) - m) * 1.4426950408889634f);
        s += pe;
        w[e] = (short)f2bf(pe);
      }
      *(short8*)ptr = w;
    }
#pragma unroll
    for (int d = 1; d < 16; d <<= 1) s += __shfl_xor(s, d, 64);
    if ((t & 15) == 0) srowv[row] = s;
  }
  __syncthreads();

  // ---- pass 2: X = P V   (wave -> (mf = rows 16, nf = d-block 16))
  const int mf = wid & 1;
  const int nf = wid >> 1;
  f32x4 xacc = {};
  for (int ch = 0; ch < 16; ++ch) {
    const int jb = ch * 128;
    if (ch) __syncthreads();     // previous chunk's VT reads done
    {
      const int j  = t >> 2;          // 0..127
      const int d0 = (t & 3) * 16;
      const unsigned short* vrow = Vp + (size_t)(jb + j) * HEAD_ + d0;
      short8 a = ((const short8*)vrow)[0];
      short8 c = ((const short8*)vrow)[1];
#pragma unroll
      for (int e = 0; e < 8; ++e) {
        VT[d0 + e][j]     = (unsigned short)a[e];
        VT[d0 + 8 + e][j] = (unsigned short)c[e];
      }
    }
    __syncthreads();
#pragma unroll
    for (int kk = 0; kk < 4; ++kk) {
      short8 pf = *(const short8*)&S[mf * 16 + lr][jb + kk * 32 + lg * 8];
      short8 vf = *(const short8*)&VT[nf * 16 + lr][kk * 32 + lg * 8];
      xacc = __builtin_amdgcn_mfma_f32_16x16x32_bf16(pf, vf, xacc, 0, 0, 0);
    }
  }

  // ---- write x in (b, i, n*64+d) layout, normalized
#pragma unroll
  for (int r = 0; r < 4; ++r) {
    const int row = mf * 16 + lg * 4 + r;
    const float v = xacc[r] / srowv[row];
    Xout[(size_t)b * (L_ * DIM_) + (size_t)(q0 + row) * DIM_ + h * HEAD_ + nf * 16 + lr] = f2bf(v);
  }
}

extern "C" void kernel_launch(void* const* d_in, const int* in_sizes, int n_in,
                              void* d_out, int out_size, void* d_ws, size_t ws_size,
                              hipStream_t stream) {
  (void)in_sizes; (void)n_in; (void)out_size; (void)ws_size;
  const float* q  = (const float*)d_in[0];
  const float* k  = (const float*)d_in[1];
  const float* v  = (const float*)d_in[2];
  const float* Wq = (const float*)d_in[3];
  const float* Wk = (const float*)d_in[4];
  const float* Wv = (const float*)d_in[5];
  const float* Wo = (const float*)d_in[6];

  unsigned short* wsu  = (unsigned short*)d_ws;
  unsigned short* qkv  = wsu;                 // 3 * SZ_ bf16
  unsigned short* xout = wsu + 3 * (size_t)SZ_;  // SZ_ bf16

  dim3 ggrid(M_ / 128, DIM_ / 128);
  gemm_bt<true, false><<<ggrid, 256, 0, stream>>>((const void*)q, Wq, (void*)(qkv + 0 * (size_t)SZ_), DIM_, DIM_);
  gemm_bt<true, false><<<ggrid, 256, 0, stream>>>((const void*)k, Wk, (void*)(qkv + 1 * (size_t)SZ_), DIM_, DIM_);
  gemm_bt<true, false><<<ggrid, 256, 0, stream>>>((const void*)v, Wv, (void*)(qkv + 2 * (size_t)SZ_), DIM_, DIM_);

  attn_kernel<<<dim3(L_ / 32, B_ * NH_), 512, 0, stream>>>(qkv, xout);

  gemm_bt<false, true><<<ggrid, 256, 0, stream>>>((const void*)xout, Wo, d_out, DIM_, DIM_);
}

// Round 3
// 312.768 us; speedup vs baseline: 1.3836x; 1.3836x over previous
//
#include <hip/hip_runtime.h>

typedef __attribute__((ext_vector_type(8))) short short8;
typedef __attribute__((ext_vector_type(4))) float f32x4;
typedef __attribute__((ext_vector_type(2))) unsigned int u32x2;

#define B_    2
#define L_    2048
#define DIM_  1024
#define NH_   16
#define HEAD_ 64
#define M_    4096            // B_*L_
#define SZ_   4194304         // M_*DIM_ elements
#define SCL   0.18033688011112043f   // 0.125 * log2(e)

__device__ __forceinline__ unsigned short f2bf(float f) {
  unsigned int u = __float_as_uint(f);
  u += 0x7FFFu + ((u >> 16) & 1u);          // RNE, finite inputs only
  return (unsigned short)(u >> 16);
}

// C[m][n] = sum_k A[m][k] * W[n][k]   (both K-contiguous; W always fp32 source)
// OUT: 0 = bf16 row-major, 1 = f32 row-major,
//      2 = bf16 VT'[bh][d][c][lrow] where head h token i dim d of the faithful
//          reshape maps to GEMM (row=grow, col=gcol) via i = (grow&127)*16 +
//          (gcol>>6), d = gcol&63, bh = grow>>7.
template<bool A_F32, int OUT>
__global__ __launch_bounds__(256) void gemm_bt(const void* __restrict__ Ap,
                                               const float* __restrict__ Wp,
                                               void* __restrict__ Cp,
                                               int Kdim, int Ndim) {
  __shared__ unsigned short Alds[128][72];
  __shared__ unsigned short Blds[128][72];
  const int t    = threadIdx.x;
  const int m0   = blockIdx.x * 128;
  const int n0   = blockIdx.y * 128;
  const int lane = t & 63;
  const int wid  = t >> 6;
  const int lr   = lane & 15;
  const int lg   = lane >> 4;
  const int wm   = (wid >> 1) * 64;
  const int wn   = (wid & 1) * 64;
  const int srow = t >> 1;
  const int skh  = (t & 1) * 32;

  f32x4 acc[4][4] = {};

  for (int kb = 0; kb < Kdim; kb += 64) {
    if (A_F32) {
      const float* arow = (const float*)Ap + (size_t)(m0 + srow) * Kdim + kb + skh;
      unsigned short tmp[32];
#pragma unroll
      for (int j = 0; j < 8; ++j) {
        f32x4 v = ((const f32x4*)arow)[j];
#pragma unroll
        for (int c = 0; c < 4; ++c) tmp[j * 4 + c] = f2bf(v[c]);
      }
#pragma unroll
      for (int j = 0; j < 4; ++j)
        *(short8*)&Alds[srow][skh + j * 8] = *(const short8*)&tmp[j * 8];
    } else {
      const unsigned short* arow = (const unsigned short*)Ap + (size_t)(m0 + srow) * Kdim + kb + skh;
#pragma unroll
      for (int j = 0; j < 4; ++j)
        *(short8*)&Alds[srow][skh + j * 8] = ((const short8*)arow)[j];
    }
    {
      const float* brow = Wp + (size_t)(n0 + srow) * Kdim + kb + skh;
      unsigned short tmp[32];
#pragma unroll
      for (int j = 0; j < 8; ++j) {
        f32x4 v = ((const f32x4*)brow)[j];
#pragma unroll
        for (int c = 0; c < 4; ++c) tmp[j * 4 + c] = f2bf(v[c]);
      }
#pragma unroll
      for (int j = 0; j < 4; ++j)
        *(short8*)&Blds[srow][skh + j * 8] = *(const short8*)&tmp[j * 8];
    }
    __syncthreads();
#pragma unroll
    for (int ks = 0; ks < 2; ++ks) {
      short8 af[4], bfv[4];
#pragma unroll
      for (int i = 0; i < 4; ++i)
        af[i] = *(const short8*)&Alds[wm + i * 16 + lr][ks * 32 + lg * 8];
#pragma unroll
      for (int i = 0; i < 4; ++i)
        bfv[i] = *(const short8*)&Blds[wn + i * 16 + lr][ks * 32 + lg * 8];
#pragma unroll
      for (int i = 0; i < 4; ++i)
#pragma unroll
        for (int j = 0; j < 4; ++j)
          acc[i][j] = __builtin_amdgcn_mfma_f32_16x16x32_bf16(af[i], bfv[j], acc[i][j], 0, 0, 0);
    }
    __syncthreads();
  }

#pragma unroll
  for (int i = 0; i < 4; ++i) {
#pragma unroll
    for (int j = 0; j < 4; ++j) {
      const int grow = m0 + wm + i * 16 + lg * 4;
      const int gcol = n0 + wn + j * 16 + lr;
      if (OUT == 2) {
        const int bh_  = grow >> 7;     // b*16 + h  (constant per block)
        const int lrow = grow & 127;    // i >> 4, r gives consecutive lrow
        const int dd   = gcol & 63;
        const int cc   = gcol >> 6;     // i & 15   (constant per wave)
        unsigned int lo = (unsigned int)f2bf(acc[i][j][0]) | ((unsigned int)f2bf(acc[i][j][1]) << 16);
        unsigned int hi = (unsigned int)f2bf(acc[i][j][2]) | ((unsigned int)f2bf(acc[i][j][3]) << 16);
        u32x2 pk; pk[0] = lo; pk[1] = hi;
        size_t off = ((size_t)(bh_ * 64 + dd) * 16 + cc) * 128 + lrow;
        *(u32x2*)&((unsigned short*)Cp)[off] = pk;
      } else {
#pragma unroll
        for (int r = 0; r < 4; ++r) {
          float v = acc[i][j][r];
          if (OUT == 1) ((float*)Cp)[(size_t)(grow + r) * Ndim + gcol] = v;
          else ((unsigned short*)Cp)[(size_t)(grow + r) * Ndim + gcol] = f2bf(v);
        }
      }
    }
  }
}

// Flash attention: 4 waves x 32 q-rows (QBLK=128), 64-key chunks.
// K staged swizzled; V staged from VT' (permuted key order p = (key&15)*4 +
// (key>>4) within each 64-chunk); P stored in the SAME permuted order, so
// the PV contraction is exact. Online softmax fully in registers.
__global__ __launch_bounds__(256) void attn_flash(const unsigned short* __restrict__ QKV,
                                                  const unsigned short* __restrict__ VTg,
                                                  unsigned short* __restrict__ Xout) {
  __shared__ unsigned short Klds[64 * 64];     // 8 KB, swizzled rows of 128B
  __shared__ unsigned short VTlds[64 * 64];    // 8 KB, permuted key order
  __shared__ unsigned short Plds[4][32 * 64];  // 4 KB per wave, permuted order

  const int t    = threadIdx.x;
  const int wv   = t >> 6;
  const int lane = t & 63;
  const int lr   = lane & 15;
  const int lg   = lane >> 4;
  // XCD-aware mapping: XCD k handles heads 4k..4k+3 -> K/VT stay L2-resident
  const int id  = blockIdx.x;
  const int xcd = id & 7;
  const int seq = id >> 3;          // 0..63
  const int bh  = xcd * 4 + (seq >> 4);
  const int qt  = seq & 15;
  const int b   = bh >> 4;
  const int h   = bh & 15;
  const size_t base = (size_t)b * (L_ * DIM_) + (size_t)h * (L_ * HEAD_);
  const unsigned short* Qp  = QKV + base;
  const unsigned short* Kp  = QKV + (size_t)SZ_ + base;
  const unsigned short* VTp = VTg + (size_t)bh * (HEAD_ * L_);
  const int q0 = qt * 128;

  short8 qf[2][2];
#pragma unroll
  for (int mf = 0; mf < 2; ++mf)
#pragma unroll
    for (int ks = 0; ks < 2; ++ks)
      qf[mf][ks] = *(const short8*)&Qp[(size_t)(q0 + wv * 32 + mf * 16 + lr) * 64 + ks * 32 + lg * 8];

  f32x4 oacc[2][4] = {};
  f32x4 lsum[2] = {};
  f32x4 mrun[2];
#pragma unroll
  for (int mf = 0; mf < 2; ++mf)
#pragma unroll
    for (int c = 0; c < 4; ++c) mrun[mf][c] = -3.0e38f;

  for (int jb = 0; jb < L_; jb += 64) {
    if (jb) __syncthreads();
    // ---- stage K chunk (64 keys x 64d), swizzled
#pragma unroll
    for (int s = 0; s < 2; ++s) {
      const int idx = s * 256 + t;
      const int row = idx >> 3;
      const int c8  = idx & 7;
      const int dst = row * 128 + ((c8 * 16) ^ ((row & 7) << 4));
      *(short8*)((char*)Klds + dst) = *(const short8*)&Kp[(size_t)(jb + row) * 64 + c8 * 8];
    }
    // ---- stage VT' chunk: row d, position p=c*4+l holds key jb + 16*l + c
#pragma unroll
    for (int s = 0; s < 4; ++s) {
      const int idx = s * 256 + t;        // 0..1023
      const int d   = idx >> 4;
      const int c   = idx & 15;
      u32x2 w = *(const u32x2*)&VTp[(size_t)d * (16 * 128) + c * 128 + (jb >> 4)];
      *(u32x2*)((char*)VTlds + d * 128 + ((c * 8) ^ ((d & 7) << 4))) = w;
    }
    __syncthreads();

    // ---- QK^T : sacc[mf][jf], q-row = mf*16+lg*4+c, key = jb + jf*16+lr
    f32x4 sacc[2][4] = {};
#pragma unroll
    for (int jf = 0; jf < 4; ++jf) {
      const int row = jf * 16 + lr;
#pragma unroll
      for (int ks = 0; ks < 2; ++ks) {
        short8 kf = *(const short8*)((const char*)Klds + row * 128 + ((ks * 64 + lg * 16) ^ ((row & 7) << 4)));
#pragma unroll
        for (int mf = 0; mf < 2; ++mf)
          sacc[mf][jf] = __builtin_amdgcn_mfma_f32_16x16x32_bf16(qf[mf][ks], kf, sacc[mf][jf], 0, 0, 0);
      }
    }

    // ---- online softmax (component c = q-row lg*4+c)
#pragma unroll
    for (int mf = 0; mf < 2; ++mf) {
      f32x4 mc = sacc[mf][0];
#pragma unroll
      for (int jf = 1; jf < 4; ++jf)
#pragma unroll
        for (int c = 0; c < 4; ++c) mc[c] = fmaxf(mc[c], sacc[mf][jf][c]);
#pragma unroll
      for (int c = 0; c < 4; ++c) {
        float m = mc[c];
        m = fmaxf(m, __shfl_xor(m, 1, 64));
        m = fmaxf(m, __shfl_xor(m, 2, 64));
        m = fmaxf(m, __shfl_xor(m, 4, 64));
        m = fmaxf(m, __shfl_xor(m, 8, 64));
        mc[c] = m;
      }
      f32x4 mnew, sc;
#pragma unroll
      for (int c = 0; c < 4; ++c) {
        mnew[c] = fmaxf(mrun[mf][c], mc[c]);
        sc[c]   = exp2f((mrun[mf][c] - mnew[c]) * SCL);
        mrun[mf][c] = mnew[c];
      }
      // P store (permuted): key jf*16+lr -> byte lr*8 + jf*2 -> one 8B store/c
#pragma unroll
      for (int c = 0; c < 4; ++c) {
        float p0 = exp2f((sacc[mf][0][c] - mnew[c]) * SCL);
        float p1 = exp2f((sacc[mf][1][c] - mnew[c]) * SCL);
        float p2 = exp2f((sacc[mf][2][c] - mnew[c]) * SCL);
        float p3 = exp2f((sacc[mf][3][c] - mnew[c]) * SCL);
        const int prow = mf * 16 + lg * 4 + c;
        u32x2 pk;
        pk[0] = (unsigned int)f2bf(p0) | ((unsigned int)f2bf(p1) << 16);
        pk[1] = (unsigned int)f2bf(p2) | ((unsigned int)f2bf(p3) << 16);
        *(u32x2*)((char*)Plds[wv] + prow * 128 + ((lr * 8) ^ ((prow & 7) << 4))) = pk;
        lsum[mf][c] = lsum[mf][c] * sc[c] + (p0 + p1 + p2 + p3);
      }
#pragma unroll
      for (int nf = 0; nf < 4; ++nf)
#pragma unroll
        for (int c = 0; c < 4; ++c) oacc[mf][nf][c] *= sc[c];
    }

    // ---- PV : oacc[mf][nf] += P * V  (both operands in permuted key order)
#pragma unroll
    for (int kk = 0; kk < 2; ++kk) {
      short8 pa[2];
#pragma unroll
      for (int mf = 0; mf < 2; ++mf) {
        const int rp = mf * 16 + lr;
        pa[mf] = *(const short8*)((const char*)Plds[wv] + rp * 128 + ((kk * 64 + lg * 16) ^ ((rp & 7) << 4)));
      }
#pragma unroll
      for (int nf = 0; nf < 4; ++nf) {
        const int rv = nf * 16 + lr;
        short8 vf = *(const short8*)((const char*)VTlds + rv * 128 + ((kk * 64 + lg * 16) ^ ((rv & 7) << 4)));
#pragma unroll
        for (int mf = 0; mf < 2; ++mf)
          oacc[mf][nf] = __builtin_amdgcn_mfma_f32_16x16x32_bf16(pa[mf], vf, oacc[mf][nf], 0, 0, 0);
      }
    }
  }

  // ---- finalize: cross-lane sum of lsum, normalize, write
#pragma unroll
  for (int mf = 0; mf < 2; ++mf) {
#pragma unroll
    for (int c = 0; c < 4; ++c) {
      float s = lsum[mf][c];
      s += __shfl_xor(s, 1, 64);
      s += __shfl_xor(s, 2, 64);
      s += __shfl_xor(s, 4, 64);
      s += __shfl_xor(s, 8, 64);
      lsum[mf][c] = s;
    }
#pragma unroll
    for (int nf = 0; nf < 4; ++nf)
#pragma unroll
      for (int c = 0; c < 4; ++c) {
        const int row = q0 + wv * 32 + mf * 16 + lg * 4 + c;
        Xout[(size_t)b * (L_ * DIM_) + (size_t)row * DIM_ + h * HEAD_ + nf * 16 + lr] =
            f2bf(oacc[mf][nf][c] / lsum[mf][c]);
      }
  }
}

extern "C" void kernel_launch(void* const* d_in, const int* in_sizes, int n_in,
                              void* d_out, int out_size, void* d_ws, size_t ws_size,
                              hipStream_t stream) {
  (void)in_sizes; (void)n_in; (void)out_size; (void)ws_size;
  const float* q  = (const float*)d_in[0];
  const float* k  = (const float*)d_in[1];
  const float* v  = (const float*)d_in[2];
  const float* Wq = (const float*)d_in[3];
  const float* Wk = (const float*)d_in[4];
  const float* Wv = (const float*)d_in[5];
  const float* Wo = (const float*)d_in[6];

  unsigned short* wsu  = (unsigned short*)d_ws;
  unsigned short* qkv  = wsu;                    // Q, K bf16 (2*SZ_)
  unsigned short* vt   = wsu + 2 * (size_t)SZ_;  // VT' (SZ_)
  unsigned short* xout = wsu + 3 * (size_t)SZ_;

  dim3 ggrid(M_ / 128, DIM_ / 128);
  gemm_bt<true, 0><<<ggrid, 256, 0, stream>>>((const void*)q, Wq, (void*)(qkv + 0 * (size_t)SZ_), DIM_, DIM_);
  gemm_bt<true, 0><<<ggrid, 256, 0, stream>>>((const void*)k, Wk, (void*)(qkv + 1 * (size_t)SZ_), DIM_, DIM_);
  gemm_bt<true, 2><<<ggrid, 256, 0, stream>>>((const void*)v, Wv, (void*)vt, DIM_, DIM_);

  attn_flash<<<512, 256, 0, stream>>>(qkv, vt, xout);

  gemm_bt<false, 1><<<ggrid, 256, 0, stream>>>((const void*)xout, Wo, d_out, DIM_, DIM_);
}